// Round 1
// baseline (7252.198 us; speedup 1.0000x reference)
//
#include <hip/hip_runtime.h>
#include <math.h>

typedef __bf16 bf16_t;
typedef __bf16 bf16x8 __attribute__((ext_vector_type(8)));
typedef float f32x4 __attribute__((ext_vector_type(4)));

#define B_ 2
#define L_ 1024
#define TXT_ 1024
#define HID_ 2048
#define INT_ 6144
#define NH_ 16
#define NKV_ 8
#define HD_ 128
#define NL_ 8
#define SW_ 128
#define EPS_ 1e-6f
#define NEGF (-3.4028234663852886e38f)

typedef const unsigned int __attribute__((address_space(1))) * gld_gptr;
typedef unsigned int __attribute__((address_space(3))) * gld_lptr;

__device__ __forceinline__ void gld16(const bf16_t* g, bf16_t* l) {
  __builtin_amdgcn_global_load_lds((gld_gptr)g, (gld_lptr)l, 16, 0, 0);
}

__device__ __forceinline__ float wred_sum(float v) {
#pragma unroll
  for (int o = 32; o; o >>= 1) v += __shfl_xor(v, o, 64);
  return v;
}
__device__ __forceinline__ float wred_max(float v) {
#pragma unroll
  for (int o = 32; o; o >>= 1) v = fmaxf(v, __shfl_xor(v, o, 64));
  return v;
}

// ---------------------------------------------------------------------------
// GEMM: C[M,N] = A[M,K] * Bt[N,K]^T   (A row-major lda, Bt row-major ldb)
// 128x128 tile, 4 waves (2x2 of 64x64), mfma 16x16x32 bf16, BK=32.
// EPI: 0 = f32 store, 1 = bf16 store, 2 = +bias f32 store,
//      3 = residual-add f32 store (aux = residual), 4 = V^T bf16 scatter store
// ---------------------------------------------------------------------------
template <int EPI>
__global__ __launch_bounds__(256) void gemm_bt(
    const bf16_t* __restrict__ A, const bf16_t* __restrict__ Bt,
    void* __restrict__ Cv, const float* __restrict__ aux, int K, int lda,
    int ldb, int ldc, long long sA, long long sB, long long sC, int bdiv) {
  __shared__ __align__(16) bf16_t As[128 * 32];
  __shared__ __align__(16) bf16_t Bs[128 * 32];
  const int z = blockIdx.z;
  A += (long long)z * sA;
  Bt += (long long)(z / bdiv) * sB;
  const int m0 = blockIdx.y * 128, n0 = blockIdx.x * 128;
  const int tid = threadIdx.x, lane = tid & 63;
  const int wave = tid >> 6, wm = wave >> 1, wn = wave & 1;
  // staging: 512 chunks of 16B per tile; this thread does chunks tid, tid+256
  const int r0 = tid >> 2, kq = (tid & 3) * 8;
  const int r1 = r0 + 64;

  f32x4 acc[4][4];
#pragma unroll
  for (int i = 0; i < 4; i++)
#pragma unroll
    for (int j = 0; j < 4; j++) acc[i][j] = (f32x4){0.f, 0.f, 0.f, 0.f};

  const bf16_t* A0 = A + (long long)(m0 + r0) * lda + kq;
  const bf16_t* A1 = A + (long long)(m0 + r1) * lda + kq;
  const bf16_t* B0 = Bt + (long long)(n0 + r0) * ldb + kq;
  const bf16_t* B1 = Bt + (long long)(n0 + r1) * ldb + kq;
  bf16_t* lA0 = As + tid * 8;
  bf16_t* lA1 = As + (tid + 256) * 8;
  bf16_t* lB0 = Bs + tid * 8;
  bf16_t* lB1 = Bs + (tid + 256) * 8;

  const int rA = lane & 15, kk = (lane >> 4) * 8;

  for (int k0 = 0; k0 < K; k0 += 32) {
    gld16(A0 + k0, lA0);
    gld16(A1 + k0, lA1);
    gld16(B0 + k0, lB0);
    gld16(B1 + k0, lB1);
    asm volatile("s_waitcnt vmcnt(0)" ::: "memory");
    __syncthreads();
    bf16x8 af[4], bfr[4];
#pragma unroll
    for (int t = 0; t < 4; t++)
      af[t] = *(const bf16x8*)(As + (wm * 64 + t * 16 + rA) * 32 + kk);
#pragma unroll
    for (int t = 0; t < 4; t++)
      bfr[t] = *(const bf16x8*)(Bs + (wn * 64 + t * 16 + rA) * 32 + kk);
#pragma unroll
    for (int tm = 0; tm < 4; tm++)
#pragma unroll
      for (int tn = 0; tn < 4; tn++)
        acc[tm][tn] = __builtin_amdgcn_mfma_f32_16x16x32_bf16(
            af[tm], bfr[tn], acc[tm][tn], 0, 0, 0);
    __syncthreads();
  }

  const int mb = m0 + wm * 64 + ((lane >> 4) << 2);
  const int nb = n0 + wn * 64 + (lane & 15);
#pragma unroll
  for (int tm = 0; tm < 4; tm++) {
#pragma unroll
    for (int tn = 0; tn < 4; tn++) {
#pragma unroll
      for (int e = 0; e < 4; e++) {
        const int m = mb + tm * 16 + e;
        const int n = nb + tn * 16;
        const float v = acc[tm][tn][e];
        if (EPI == 0) {
          ((float*)Cv)[(long long)z * sC + (long long)m * ldc + n] = v;
        } else if (EPI == 1) {
          ((bf16_t*)Cv)[(long long)z * sC + (long long)m * ldc + n] =
              (bf16_t)v;
        } else if (EPI == 2) {
          ((float*)Cv)[(long long)m * ldc + n] = v + aux[n];
        } else if (EPI == 3) {
          ((float*)Cv)[(long long)m * ldc + n] =
              v + aux[(long long)m * ldc + n];
        } else {  // EPI == 4: store V^T  [B,NKV,HD,L] from C[m = b*L+l][n = kvh*HD+d]
          const int b = m >> 10, l = m & 1023, kvh = n >> 7, d = n & 127;
          ((bf16_t*)Cv)[(((long long)(b * NKV_ + kvh) * HD_ + d) << 10) + l] =
              (bf16_t)v;
        }
      }
    }
  }
}

// fp32 [R][C] -> bf16 [C][R]
__global__ void transpose_w(const float* __restrict__ src,
                            bf16_t* __restrict__ dst, int R, int C) {
  __shared__ float t[32][33];
  const int c = blockIdx.x * 32 + threadIdx.x;
  const int rbase = blockIdx.y * 32;
#pragma unroll
  for (int i = 0; i < 4; i++) {
    const int r = rbase + threadIdx.y + i * 8;
    t[threadIdx.y + i * 8][threadIdx.x] = src[(long long)r * C + c];
  }
  __syncthreads();
  const int r2 = rbase + threadIdx.x;
#pragma unroll
  for (int i = 0; i < 4; i++) {
    const int c2 = blockIdx.x * 32 + threadIdx.y + i * 8;
    dst[(long long)c2 * R + r2] = (bf16_t)t[threadIdx.x][threadIdx.y + i * 8];
  }
}

__global__ void cvt_bf16(const float* __restrict__ src,
                         bf16_t* __restrict__ dst, int n) {
  const int i = blockIdx.x * 256 + threadIdx.x;
  if (i < n) dst[i] = (bf16_t)src[i];
}

template <bool OUT_BF16>
__global__ __launch_bounds__(256) void rmsnorm_k(const float* __restrict__ x,
                                                 const float* __restrict__ w,
                                                 void* __restrict__ out) {
  __shared__ float sm[4];
  const long long row = blockIdx.x;
  const float* xr = x + row * HID_;
  float v[8];
  float ss = 0.f;
#pragma unroll
  for (int kq = 0; kq < 8; kq++) {
    v[kq] = xr[threadIdx.x + kq * 256];
    ss += v[kq] * v[kq];
  }
  ss = wred_sum(ss);
  const int lane = threadIdx.x & 63, wv = threadIdx.x >> 6;
  if (lane == 0) sm[wv] = ss;
  __syncthreads();
  const float tot = sm[0] + sm[1] + sm[2] + sm[3];
  const float r = rsqrtf(tot * (1.f / HID_) + EPS_);
#pragma unroll
  for (int kq = 0; kq < 8; kq++) {
    const int j = threadIdx.x + kq * 256;
    const float o = w[j] * v[kq] * r;
    if (OUT_BF16)
      ((bf16_t*)out)[row * HID_ + j] = (bf16_t)o;
    else
      ((float*)out)[row * HID_ + j] = o;
  }
}

// per-(b,l,head) RMSNorm over HD + RoPE; writes q [B,NH,L,HD], k [B,NKV,L,HD]
__global__ __launch_bounds__(64) void qknorm_rope(
    const bf16_t* __restrict__ qpre, const bf16_t* __restrict__ kpre,
    const float* __restrict__ wq, const float* __restrict__ wk,
    bf16_t* __restrict__ qout, bf16_t* __restrict__ kout) {
  const int bl = blockIdx.x;  // b*L + l
  const int b = bl >> 10, l = bl & 1023;
  const int hy = blockIdx.y;  // 0..NH-1 -> q; NH..NH+NKV-1 -> k
  const int j = threadIdx.x;  // 0..63
  const bf16_t* src;
  const float* w;
  bf16_t* dst;
  if (hy < NH_) {
    src = qpre + (long long)bl * (NH_ * HD_) + hy * HD_;
    w = wq;
    dst = qout + ((long long)(b * NH_ + hy) * L_ + l) * HD_;
  } else {
    const int hk = hy - NH_;
    src = kpre + (long long)bl * (NKV_ * HD_) + hk * HD_;
    w = wk;
    dst = kout + ((long long)(b * NKV_ + hk) * L_ + l) * HD_;
  }
  const float x0 = (float)src[j], x1 = (float)src[j + 64];
  const float ss = wred_sum(x0 * x0 + x1 * x1);
  const float r = rsqrtf(ss * (1.f / HD_) + EPS_);
  const float n0 = x0 * r * w[j], n1 = x1 * r * w[j + 64];
  const float inv = powf(1.0e6f, -(float)j * (1.f / 64.f));
  const float ang = (float)l * inv;
  float sn, cs;
  sincosf(ang, &sn, &cs);
  dst[j] = (bf16_t)(n0 * cs - n1 * sn);
  dst[j + 64] = (bf16_t)(n1 * cs + n0 * sn);
}

// softmax over fp32 score rows; writes bf16 probs in-place (row pitch 2L bf16)
__global__ __launch_bounds__(256) void softmax_k(float* __restrict__ scores,
                                                 const int* __restrict__ amask,
                                                 int sliding) {
  __shared__ float sm[4];
  const int z = blockIdx.y;  // b*NH + h
  const int b = z >> 4;
  const int i = blockIdx.x;
  float* row = scores + ((long long)z * L_ + i) * L_;
  bf16_t* prow = (bf16_t*)row;
  const float scale = 0.08838834764831845f;
  float v[4];
  float mx = -INFINITY;
#pragma unroll
  for (int kq = 0; kq < 4; kq++) {
    const int j = threadIdx.x + kq * 256;
    int d = i - j;
    if (d < 0) d = -d;
    const bool keep = (amask[b * L_ + j] != 0) && (!sliding || d <= SW_);
    v[kq] = keep ? row[j] * scale : NEGF;
    mx = fmaxf(mx, v[kq]);
  }
  mx = wred_max(mx);
  const int lane = threadIdx.x & 63, wv = threadIdx.x >> 6;
  if (lane == 0) sm[wv] = mx;
  __syncthreads();
  mx = fmaxf(fmaxf(sm[0], sm[1]), fmaxf(sm[2], sm[3]));
  __syncthreads();
  float s = 0.f;
#pragma unroll
  for (int kq = 0; kq < 4; kq++) {
    v[kq] = expf(v[kq] - mx);
    s += v[kq];
  }
  s = wred_sum(s);
  if (lane == 0) sm[wv] = s;
  __syncthreads();
  s = sm[0] + sm[1] + sm[2] + sm[3];
  const float rinv = 1.f / s;
#pragma unroll
  for (int kq = 0; kq < 4; kq++)
    prow[threadIdx.x + kq * 256] = (bf16_t)(v[kq] * rinv);
}

__global__ void silu_mul_k(const bf16_t* __restrict__ g,
                           const bf16_t* __restrict__ u,
                           bf16_t* __restrict__ o, long long n) {
  const long long idx = (long long)blockIdx.x * 256 + threadIdx.x;
  if (idx < n) {
    const float gv = (float)g[idx];
    const float uv = (float)u[idx];
    o[idx] = (bf16_t)((gv / (1.f + expf(-gv))) * uv);
  }
}

// o_tmp [B,NH,L,HD] bf16 -> o_buf [B,L,NH*HD] bf16 (16B chunks)
__global__ void reshape_o(const bf16_t* __restrict__ src,
                          bf16_t* __restrict__ dst) {
  const int c = blockIdx.x * 256 + threadIdx.x;  // 0..524287
  const int o = c & 15;
  const int r = c >> 4;  // (b*NH + h)*L + l
  const int l = r & 1023;
  const int h = (r >> 10) & 15;
  const int b = r >> 14;
  const uint4* s4 = (const uint4*)src + c;
  uint4* d4 = (uint4*)(dst + ((long long)(b * L_ + l) * (NH_ * HD_) + h * HD_)) + o;
  *d4 = *s4;
}

static void launch_gemm(int epi, dim3 grid, hipStream_t s, const bf16_t* A,
                        const bf16_t* Bt, void* C, const float* aux, int K,
                        int lda, int ldb, int ldc, long long sA, long long sB,
                        long long sC, int bdiv) {
  switch (epi) {
    case 0: gemm_bt<0><<<grid, 256, 0, s>>>(A, Bt, C, aux, K, lda, ldb, ldc, sA, sB, sC, bdiv); break;
    case 1: gemm_bt<1><<<grid, 256, 0, s>>>(A, Bt, C, aux, K, lda, ldb, ldc, sA, sB, sC, bdiv); break;
    case 2: gemm_bt<2><<<grid, 256, 0, s>>>(A, Bt, C, aux, K, lda, ldb, ldc, sA, sB, sC, bdiv); break;
    case 3: gemm_bt<3><<<grid, 256, 0, s>>>(A, Bt, C, aux, K, lda, ldb, ldc, sA, sB, sC, bdiv); break;
    default: gemm_bt<4><<<grid, 256, 0, s>>>(A, Bt, C, aux, K, lda, ldb, ldc, sA, sB, sC, bdiv); break;
  }
}

extern "C" void kernel_launch(void* const* d_in, const int* in_sizes, int n_in,
                              void* d_out, int out_size, void* d_ws,
                              size_t ws_size, hipStream_t stream) {
  const float* x = (const float*)d_in[0];
  const int* amask = (const int*)d_in[1];
  const float* W_embed = (const float*)d_in[2];
  const float* b_embed = (const float*)d_in[3];
  const float* Wq = (const float*)d_in[4];
  const float* Wk = (const float*)d_in[5];
  const float* Wv = (const float*)d_in[6];
  const float* Wo = (const float*)d_in[7];
  const float* w_in_ln = (const float*)d_in[8];
  const float* w_post_ln = (const float*)d_in[9];
  const float* w_qn = (const float*)d_in[10];
  const float* w_kn = (const float*)d_in[11];
  const float* Wg = (const float*)d_in[12];
  const float* Wu = (const float*)d_in[13];
  const float* Wd = (const float*)d_in[14];
  const float* w_final = (const float*)d_in[15];
  float* out = (float*)d_out;

  char* ws = (char*)d_ws;
  size_t off = 0;
  auto alloc = [&](size_t bytes) -> void* {
    void* p = (void*)(ws + off);
    off += (bytes + 255) & ~(size_t)255;
    return p;
  };
  bf16_t* wT_q = (bf16_t*)alloc((size_t)2048 * 2048 * 2);
  bf16_t* wT_k = (bf16_t*)alloc((size_t)1024 * 2048 * 2);
  bf16_t* wT_v = (bf16_t*)alloc((size_t)1024 * 2048 * 2);
  bf16_t* wT_o = (bf16_t*)alloc((size_t)2048 * 2048 * 2);
  bf16_t* wT_g = (bf16_t*)alloc((size_t)6144 * 2048 * 2);
  bf16_t* wT_u = (bf16_t*)alloc((size_t)6144 * 2048 * 2);
  bf16_t* wT_d = (bf16_t*)alloc((size_t)2048 * 6144 * 2);
  bf16_t* wT_e = (bf16_t*)alloc((size_t)2048 * 1024 * 2);
  bf16_t* x_bf = (bf16_t*)alloc((size_t)2048 * 1024 * 2);
  float* h = (float*)alloc((size_t)2048 * 2048 * 4);
  bf16_t* hn = (bf16_t*)alloc((size_t)2048 * 2048 * 2);
  bf16_t* qpre = (bf16_t*)alloc((size_t)2048 * 2048 * 2);
  bf16_t* kpre = (bf16_t*)alloc((size_t)2048 * 1024 * 2);
  bf16_t* qb = (bf16_t*)alloc((size_t)2048 * 2048 * 2);
  bf16_t* kb = (bf16_t*)alloc((size_t)2048 * 1024 * 2);
  bf16_t* vT = (bf16_t*)alloc((size_t)2048 * 1024 * 2);
  float* scores = (float*)alloc((size_t)32 * 1024 * 1024 * 4);
  bf16_t* o_tmp = (bf16_t*)alloc((size_t)2048 * 2048 * 2);
  bf16_t* o_buf = (bf16_t*)alloc((size_t)2048 * 2048 * 2);
  bf16_t* gbuf = (bf16_t*)alloc((size_t)2048 * 6144 * 2);
  bf16_t* ubuf = (bf16_t*)alloc((size_t)2048 * 6144 * 2);
  bf16_t* actb = (bf16_t*)alloc((size_t)2048 * 6144 * 2);
  (void)ws_size;
  (void)in_sizes;
  (void)n_in;
  (void)out_size;

  const int BL = B_ * L_;  // 2048
  const dim3 tb(32, 8);

  // x -> bf16; W_embed^T; embed GEMM (+bias) -> h fp32
  cvt_bf16<<<(BL * TXT_ + 255) / 256, 256, 0, stream>>>(x, x_bf, BL * TXT_);
  transpose_w<<<dim3(HID_ / 32, TXT_ / 32), tb, 0, stream>>>(W_embed, wT_e,
                                                             TXT_, HID_);
  launch_gemm(2, dim3(HID_ / 128, BL / 128, 1), stream, x_bf, wT_e, h, b_embed,
              TXT_, TXT_, TXT_, HID_, 0, 0, 0, 1);

  for (int li = 0; li < NL_; li++) {
    const float* Wq_i = Wq + (size_t)li * HID_ * (NH_ * HD_);
    const float* Wk_i = Wk + (size_t)li * HID_ * (NKV_ * HD_);
    const float* Wv_i = Wv + (size_t)li * HID_ * (NKV_ * HD_);
    const float* Wo_i = Wo + (size_t)li * (NH_ * HD_) * HID_;
    const float* Wg_i = Wg + (size_t)li * HID_ * INT_;
    const float* Wu_i = Wu + (size_t)li * HID_ * INT_;
    const float* Wd_i = Wd + (size_t)li * INT_ * HID_;

    transpose_w<<<dim3(2048 / 32, 2048 / 32), tb, 0, stream>>>(Wq_i, wT_q, 2048, 2048);
    transpose_w<<<dim3(1024 / 32, 2048 / 32), tb, 0, stream>>>(Wk_i, wT_k, 2048, 1024);
    transpose_w<<<dim3(1024 / 32, 2048 / 32), tb, 0, stream>>>(Wv_i, wT_v, 2048, 1024);
    transpose_w<<<dim3(2048 / 32, 2048 / 32), tb, 0, stream>>>(Wo_i, wT_o, 2048, 2048);
    transpose_w<<<dim3(6144 / 32, 2048 / 32), tb, 0, stream>>>(Wg_i, wT_g, 2048, 6144);
    transpose_w<<<dim3(6144 / 32, 2048 / 32), tb, 0, stream>>>(Wu_i, wT_u, 2048, 6144);
    transpose_w<<<dim3(2048 / 32, 6144 / 32), tb, 0, stream>>>(Wd_i, wT_d, 6144, 2048);

    rmsnorm_k<true><<<BL, 256, 0, stream>>>(h, w_in_ln + li * HID_, hn);

    launch_gemm(1, dim3(2048 / 128, BL / 128, 1), stream, hn, wT_q, qpre,
                nullptr, 2048, 2048, 2048, 2048, 0, 0, 0, 1);
    launch_gemm(1, dim3(1024 / 128, BL / 128, 1), stream, hn, wT_k, kpre,
                nullptr, 2048, 2048, 2048, 1024, 0, 0, 0, 1);
    launch_gemm(4, dim3(1024 / 128, BL / 128, 1), stream, hn, wT_v, vT,
                nullptr, 2048, 2048, 2048, 0, 0, 0, 0, 1);

    qknorm_rope<<<dim3(BL, NH_ + NKV_), 64, 0, stream>>>(
        qpre, kpre, w_qn + li * HD_, w_kn + li * HD_, qb, kb);

    // scores[z=b*NH+h] = Q[z] * K[z/2]^T
    launch_gemm(0, dim3(L_ / 128, L_ / 128, B_ * NH_), stream, qb, kb, scores,
                nullptr, HD_, HD_, HD_, L_, (long long)L_ * HD_,
                (long long)L_ * HD_, (long long)L_ * L_, 2);

    softmax_k<<<dim3(L_, B_ * NH_), 256, 0, stream>>>(scores, amask,
                                                      (li % 2 == 0) ? 1 : 0);

    // O[z] = P[z] * V^T[z/2]^T ; P is bf16 overlaid on fp32 rows (lda = 2L)
    launch_gemm(1, dim3(HD_ / 128, L_ / 128, B_ * NH_), stream,
                (const bf16_t*)scores, vT, o_tmp, nullptr, L_, 2 * L_, L_, HD_,
                (long long)L_ * 2 * L_, (long long)HD_ * L_,
                (long long)L_ * HD_, 2);

    reshape_o<<<(B_ * NH_ * L_ * HD_ / 8) / 256, 256, 0, stream>>>(o_tmp, o_buf);

    launch_gemm(3, dim3(2048 / 128, BL / 128, 1), stream, o_buf, wT_o, h, h,
                2048, 2048, 2048, 2048, 0, 0, 0, 1);

    rmsnorm_k<true><<<BL, 256, 0, stream>>>(h, w_post_ln + li * HID_, hn);

    launch_gemm(1, dim3(6144 / 128, BL / 128, 1), stream, hn, wT_g, gbuf,
                nullptr, 2048, 2048, 2048, 6144, 0, 0, 0, 1);
    launch_gemm(1, dim3(6144 / 128, BL / 128, 1), stream, hn, wT_u, ubuf,
                nullptr, 2048, 2048, 2048, 6144, 0, 0, 0, 1);
    silu_mul_k<<<(BL * INT_ + 255) / 256, 256, 0, stream>>>(
        gbuf, ubuf, actb, (long long)BL * INT_);
    launch_gemm(3, dim3(2048 / 128, BL / 128, 1), stream, actb, wT_d, h, h,
                6144, 6144, 6144, 2048, 0, 0, 0, 1);
  }

  rmsnorm_k<false><<<BL, 256, 0, stream>>>(h, w_final, out);
}